// Round 12
// baseline (1523.440 us; speedup 1.0000x reference)
//
#include <hip/hip_runtime.h>
#include <hip/hip_bf16.h>

typedef __bf16 bf16x8 __attribute__((ext_vector_type(8)));
typedef float f32x4 __attribute__((ext_vector_type(4)));
typedef float f32x16 __attribute__((ext_vector_type(16)));
typedef short s16x8 __attribute__((ext_vector_type(8)));
typedef unsigned u32x4 __attribute__((ext_vector_type(4)));

#define LOG2E 1.44269504088896f

__device__ __forceinline__ void gll16(const void* g, void* l) {
  __builtin_amdgcn_global_load_lds((const __attribute__((address_space(1))) void*)g,
                                   (__attribute__((address_space(3))) void*)l, 16, 0, 0);
}

__device__ __forceinline__ unsigned cvt_pk_bf16(float lo, float hi_) {
  unsigned r;
  asm("v_cvt_pk_bf16_f32 %0, %1, %2" : "=v"(r) : "v"(lo), "v"(hi_));
  return r;
}
__device__ __forceinline__ void pswap(unsigned& a, unsigned& b) {
  asm("v_permlane32_swap_b32 %0, %1" : "+v"(a), "+v"(b));
}

// swizzle for the V-transpose kernel's internal LDS tile
__device__ __forceinline__ int swzv(int row, int cbyte) {
  return (row * 128 + cbyte) ^ (((row >> 3) & 7) << 4);
}

// ---------------- weight transpose f32[K][N] -> bf16[N][K] ----------------
__global__ __launch_bounds__(256)
void wtrans_kernel(const float* __restrict__ in, __hip_bfloat16* __restrict__ out,
                   int K, int N, size_t lstride_in, size_t lstride_out) {
  __shared__ float tile[64][65];
  const size_t mi = (size_t)blockIdx.z * lstride_in;
  const size_t mo = (size_t)blockIdx.z * lstride_out;
  const int k0 = blockIdx.x * 64, n0 = blockIdx.y * 64;
  const int t = threadIdx.x;
  const int r = t >> 4, c = (t & 15) * 4;
#pragma unroll
  for (int it = 0; it < 4; ++it) {
    const float4 v = *(const float4*)&in[mi + (size_t)(k0 + it * 16 + r) * N + n0 + c];
    tile[it * 16 + r][c + 0] = v.x; tile[it * 16 + r][c + 1] = v.y;
    tile[it * 16 + r][c + 2] = v.z; tile[it * 16 + r][c + 3] = v.w;
  }
  __syncthreads();
#pragma unroll
  for (int it = 0; it < 4; ++it) {
    const int n = it * 16 + r;
    __hip_bfloat16 hb[4];
#pragma unroll
    for (int j = 0; j < 4; ++j) hb[j] = __float2bfloat16(tile[c + j][n]);
    *(uint2*)&out[mo + (size_t)(n0 + n) * K + k0 + c] = *(uint2*)hb;
  }
}

// ---------------- key bias + per-tile mask bitmasks ----------------
__global__ void kbias_kernel(const int* __restrict__ x, float* __restrict__ kb) {
  const int i = blockIdx.x * 256 + threadIdx.x;
  kb[i] = (x[i] == 0) ? -1e30f : 0.f;
}

// tm[b*2+0] = bit kt set if 64-key tile kt fully padded; tm[b*2+1] = partial pad
__global__ void tmask_kernel(const int* __restrict__ x, unsigned* __restrict__ tm) {
  const int tid = threadIdx.x;
  const int w = tid >> 6, lane = tid & 63;
  const int b = w * 2 + (lane >> 5), kt = lane & 31;
  int all64 = 1, any = 0;
  for (int i = 0; i < 64; ++i) {
    const int v = (x[b * 2048 + kt * 64 + i] == 0);
    any |= v; all64 &= v;
  }
  const unsigned long long bf = __ballot(all64);
  const unsigned long long bp = __ballot(any && !all64);
  if (lane == 0) { tm[(w * 2) * 2] = (unsigned)bf; tm[(w * 2) * 2 + 1] = (unsigned)bp; }
  if (lane == 32) { tm[(w * 2 + 1) * 2] = (unsigned)(bf >> 32); tm[(w * 2 + 1) * 2 + 1] = (unsigned)(bp >> 32); }
}

// ---------------- bias concat [L][512]x3 -> [L][1536] ----------------
__global__ void bcat_kernel(const float* __restrict__ bq, const float* __restrict__ bk,
                            const float* __restrict__ bv, float* __restrict__ o) {
  const int l = blockIdx.x, t = threadIdx.x;
  o[l * 1536 + t] = bq[l * 512 + t];
  o[l * 1536 + 512 + t] = bk[l * 512 + t];
  o[l * 1536 + 1024 + t] = bv[l * 512 + t];
}

// ---------------- embedding + positional (bf16 h only) ----------------
__global__ __launch_bounds__(128)
void embed_kernel(const int* __restrict__ x, const float* __restrict__ emb,
                  const float* __restrict__ pe, __hip_bfloat16* __restrict__ hbf) {
  const int row = blockIdx.x;
  const int t = row & 2047;
  const int tok = x[row];
  const int d = threadIdx.x * 4;
  const float4 e = *(const float4*)&emb[(size_t)tok * 512 + d];
  const float4 p = *(const float4*)&pe[(size_t)t * 512 + d];
  __hip_bfloat16 hb[4] = {__float2bfloat16(e.x + p.x), __float2bfloat16(e.y + p.y),
                          __float2bfloat16(e.z + p.z), __float2bfloat16(e.w + p.w)};
  *(uint2*)&hbf[(size_t)row * 512 + d] = *(uint2*)hb;
}

// ---------------- 128^2 GEMM with XCD-chunked block swizzle ----------------
// remap so all Ny column-blocks of consecutive row-panels land on one XCD:
// A-panel then fetched ~once from HBM instead of up to 8x (per-XCD L2s).
template <bool RELU, bool ADDRES>
__global__ __launch_bounds__(256, 4)
void gemm_kernel(const __hip_bfloat16* __restrict__ A, const __hip_bfloat16* __restrict__ Bt,
                 const float* __restrict__ bias, const __hip_bfloat16* __restrict__ res,
                 __hip_bfloat16* __restrict__ Cb, int M, int N, int K) {
  constexpr int BK = 32;
  __shared__ __hip_bfloat16 Ash[2][128 * BK];
  __shared__ __hip_bfloat16 Bsh[2][128 * BK];
  const int Mx = gridDim.x, Ny = gridDim.y;
  const int flat = blockIdx.y * Mx + blockIdx.x;
  const int per = (Mx * Ny) >> 3;          // grids chosen with Mx*Ny % 8 == 0
  const int f = (flat & 7) * per + (flat >> 3);
  const int m0 = (f / Ny) * 128, n0 = (f % Ny) * 128;
  const int tid = threadIdx.x;
  const int lane = tid & 63, wid = tid >> 6;
  const int wr = wid >> 1, wc = wid & 1;
  const int cl = lane & 15, gr = lane >> 4;

  const int ar = tid >> 2;
  const int ac = (tid & 3) << 3;
  const __hip_bfloat16* Ag = A + (size_t)(m0 + ar) * K + ac;
  const __hip_bfloat16* Bg = Bt + (size_t)(n0 + ar) * K + ac;
  const int ldst = tid * 8;

  f32x4 acc[4][4] = {};
  const int KT = K / BK;

  auto stage = [&](int buf, int kt) {
    const size_t ko = (size_t)kt * BK;
    gll16(Ag + ko, &Ash[buf][ldst]);
    gll16(Ag + ko + (size_t)64 * K, &Ash[buf][2048 + ldst]);
    gll16(Bg + ko, &Bsh[buf][ldst]);
    gll16(Bg + ko + (size_t)64 * K, &Bsh[buf][2048 + ldst]);
  };

  stage(0, 0);
  __syncthreads();
  int cur = 0;
  for (int kt = 0; kt < KT; ++kt) {
    if (kt + 1 < KT) stage(cur ^ 1, kt + 1);
    bf16x8 aF[4], bF[4];
#pragma unroll
    for (int i = 0; i < 4; ++i) {
      aF[i] = *(const bf16x8*)&Ash[cur][(wr * 64 + i * 16 + cl) * BK + gr * 8];
      bF[i] = *(const bf16x8*)&Bsh[cur][(wc * 64 + i * 16 + cl) * BK + gr * 8];
    }
#pragma unroll
    for (int i = 0; i < 4; ++i)
#pragma unroll
      for (int j = 0; j < 4; ++j)
        acc[i][j] = __builtin_amdgcn_mfma_f32_16x16x32_bf16(aF[i], bF[j], acc[i][j], 0, 0, 0);
    __syncthreads();
    cur ^= 1;
  }

  float bv[4];
#pragma unroll
  for (int j = 0; j < 4; ++j) bv[j] = bias[n0 + wc * 64 + j * 16 + cl];
#pragma unroll
  for (int i = 0; i < 4; ++i) {
    const int rowb = m0 + wr * 64 + i * 16 + gr * 4;
#pragma unroll
    for (int rr = 0; rr < 4; ++rr) {
      const size_t ro = (size_t)(rowb + rr) * N;
#pragma unroll
      for (int j = 0; j < 4; ++j) {
        float v = acc[i][j][rr] + bv[j];
        const int col = n0 + wc * 64 + j * 16 + cl;
        if (ADDRES) v += __bfloat162float(res[ro + col]);
        if (RELU) v = v > 0.f ? v : 0.f;
        Cb[ro + col] = __float2bfloat16(v);
      }
    }
  }
}

// ---------------- V transpose: qkv[M][1536] (V section) -> vt[b*8+h][64][2048] ----------------
__global__ __launch_bounds__(256)
void vtrans_kernel(const __hip_bfloat16* __restrict__ qkv, __hip_bfloat16* __restrict__ vt) {
  constexpr int T = 2048, QS = 1536;
  __shared__ __hip_bfloat16 tile[64 * 64];
  const int tt = blockIdx.x, bh = blockIdx.y;
  const int b = bh >> 3, h = bh & 7;
  const int tid = threadIdx.x;
  const int r = tid >> 2, c0 = (tid & 3) * 16;
  const __hip_bfloat16* src = qkv + ((size_t)(b * T + tt * 64 + r)) * QS + 1024 + h * 64 + c0;
  *(bf16x8*)((char*)tile + swzv(r, c0 * 2)) = *(const bf16x8*)src;
  *(bf16x8*)((char*)tile + swzv(r, c0 * 2 + 16)) = *(const bf16x8*)(src + 8);
  __syncthreads();
  __hip_bfloat16 buf[16];
#pragma unroll
  for (int j = 0; j < 16; ++j)
    buf[j] = *(__hip_bfloat16*)((char*)tile + swzv(c0 + j, r * 2));
  __hip_bfloat16* dst = vt + ((size_t)(bh * 64 + r)) * T + tt * 64 + c0;
  *(uint4*)dst = ((uint4*)buf)[0];
  *(uint4*)(dst + 8) = ((uint4*)buf)[1];
}

// ---------------- flash attention: 8 waves, Q-block=256, KV tile=128, no-max softmax ----
// 16 tiles (half the barriers of KVBLK=64); K rows 128B (3-bit swz), V rows 256B (4-bit swz).
__global__ __launch_bounds__(512, 2)
void attn10_kernel(const __hip_bfloat16* __restrict__ qkv, const __hip_bfloat16* __restrict__ Vt,
                   const float* __restrict__ kbias, const unsigned* __restrict__ tmaskg,
                   __hip_bfloat16* __restrict__ Og) {
  constexpr int T = 2048, NT = T / 128, QS = 1536;
  __shared__ __hip_bfloat16 Ks[2][128 * 64];   // 32KB: 128 key-rows x 64 d
  __shared__ __hip_bfloat16 Vs[2][64 * 128];   // 32KB: 64 d-rows x 128 keys
  __shared__ float bc[8][32];
  const int bid = blockIdx.x;
  const int wg = (bid & 7) * 64 + (bid >> 3);
  const int qb = wg & 7, bh = wg >> 3;
  const int b = bh >> 3, h = bh & 7;
  const int tid = threadIdx.x;
  const int w = tid >> 6, lane = tid & 63;
  const int col = lane & 31, hi = lane >> 5;
  const unsigned fullm = tmaskg[b * 2], partm = tmaskg[b * 2 + 1];

  // K staging (rule #21: linear LDS dest, inverse-swizzled global source)
  const int sr = tid >> 3;                    // key row 0..63 (and +64)
  const int sc = 8 * ((tid & 7) ^ (sr & 7));
  const __hip_bfloat16* kp = qkv + ((size_t)(b * T + sr)) * QS + 512 + h * 64 + sc;
  // V staging: d-row vr (and +32), 16 chunks per 256B row, 4-bit swizzle
  const int vr = tid >> 4;                    // 0..31
  const int vsc = 8 * ((tid & 15) ^ (vr & 15));
  const __hip_bfloat16* vp = Vt + ((size_t)(bh * 64 + vr)) * T + vsc;

  auto stage = [&](int buf, int kt) {
    const size_t ko = (size_t)kt * 128 * QS;
    gll16(kp + ko, (char*)Ks[buf] + tid * 16);
    gll16(kp + ko + (size_t)64 * QS, (char*)Ks[buf] + 8192 + tid * 16);
    const int vo = kt * 128;
    gll16(vp + vo, (char*)Vs[buf] + tid * 16);
    gll16(vp + vo + (size_t)32 * T, (char*)Vs[buf] + 8192 + tid * 16);
  };

  // Q fragments (B-operand), pre-scaled by 0.125*log2(e)
  const float qscale = 0.125f * LOG2E;
  s16x8 qf[4];
  {
    const __hip_bfloat16* qptr =
        qkv + ((size_t)(b * T + qb * 256 + w * 32 + col)) * QS + h * 64 + 8 * hi;
#pragma unroll
    for (int ks = 0; ks < 4; ++ks) {
      s16x8 raw = *(const s16x8*)(qptr + ks * 16);
#pragma unroll
      for (int j = 0; j < 8; ++j) {
        const unsigned u = ((unsigned)(unsigned short)raw[j]) << 16;
        const float f = __uint_as_float(u) * qscale;
        const __hip_bfloat16 hb = __float2bfloat16(f);
        raw[j] = *(const short*)&hb;
      }
      qf[ks] = raw;
    }
  }

  stage(0, 0);
  __syncthreads();

  f32x16 o0 = {}, o1 = {};
  f32x4 lacc = {};

  for (int kt = 0; kt < NT; ++kt) {
    const int cur = kt & 1;
    if (kt + 1 < NT) stage(cur ^ 1, kt + 1);

    const char* kbase = (const char*)Ks[cur];
    const char* vbase = (const char*)Vs[cur];
    const float* kbp = kbias + (size_t)b * T + kt * 128;

#pragma unroll
    for (int kb2 = 0; kb2 < 4; ++kb2) {
      const int mb = kt * 2 + (kb2 >> 1);     // 64-key mask bit
      if ((fullm >> mb) & 1) continue;

      // S^T = K_chunk(32 keys) . Q^T (lane's col = its query), log2 domain
      f32x16 s = {};
      {
        const char* khalf = kbase + kb2 * 4096;
        __builtin_amdgcn_s_setprio(1);
#pragma unroll
        for (int ks = 0; ks < 4; ++ks) {
          const int sl = ((2 * ks + hi) ^ (col & 7)) * 16;
          const bf16x8 k8 = *(const bf16x8*)(khalf + col * 128 + sl);
          s = __builtin_amdgcn_mfma_f32_32x32x16_bf16(k8, *(const bf16x8*)&qf[ks], s, 0, 0, 0);
        }
        __builtin_amdgcn_s_setprio(0);
      }

      if ((partm >> mb) & 1) {
#pragma unroll
        for (int r = 0; r < 16; ++r) {
          const int k16 = (r & 3) + 8 * (r >> 2) + 4 * hi;
          s[r] += kbp[kb2 * 32 + k16];
        }
      }

      // raw v_exp_f32 (scores bounded; -1e30 -> 0); defer l-reduction to epilogue
#pragma unroll
      for (int r = 0; r < 16; ++r) {
        s[r] = __builtin_amdgcn_exp2f(s[r]);
        lacc[r & 3] += s[r];
      }

      // P -> bf16 A-frags (cvt_pk + permlane32_swap), PV accumulate
#pragma unroll
      for (int half = 0; half < 2; ++half) {
        const int ks = kb2 * 2 + half;        // key-chunk pair index 0..7
        const int rb = half * 8;
        unsigned wa = cvt_pk_bf16(s[rb + 0], s[rb + 1]);
        unsigned wb = cvt_pk_bf16(s[rb + 2], s[rb + 3]);
        unsigned wc = cvt_pk_bf16(s[rb + 4], s[rb + 5]);
        unsigned wd = cvt_pk_bf16(s[rb + 6], s[rb + 7]);
        pswap(wa, wc);
        pswap(wb, wd);
        const u32x4 paw = {wa, wb, wc, wd};
        const bf16x8 pa = __builtin_bit_cast(bf16x8, paw);
        const int sl = ((2 * ks + hi) ^ (col & 15)) * 16;
        const bf16x8 v0 = *(const bf16x8*)(vbase + col * 256 + sl);
        const bf16x8 v1 = *(const bf16x8*)(vbase + 8192 + col * 256 + sl);
        __builtin_amdgcn_s_setprio(1);
        o0 = __builtin_amdgcn_mfma_f32_32x32x16_bf16(pa, v0, o0, 0, 0, 0);
        o1 = __builtin_amdgcn_mfma_f32_32x32x16_bf16(pa, v1, o1, 0, 0, 0);
        __builtin_amdgcn_s_setprio(0);
      }
    }
    __syncthreads();
  }

  // epilogue: l-reduction (tree over 4 + half-swap), 1/l broadcast, store
  float sm[4];
#pragma unroll
  for (int r = 0; r < 4; ++r) sm[r] = lacc[r];
  sm[0] += sm[2]; sm[1] += sm[3]; sm[0] += sm[1];
  const float lrun = sm[0] + __shfl_xor(sm[0], 32);

  bc[w][col] = 1.f / lrun;
  __hip_bfloat16* op = Og + ((size_t)(b * T + qb * 256 + w * 32)) * 512 + h * 64;
#pragma unroll
  for (int r = 0; r < 16; ++r) {
    const int query = (r & 3) + 8 * (r >> 2) + 4 * hi;
    const float li = bc[w][query];
    op[(size_t)query * 512 + col] = __float2bfloat16(o0[r] * li);
    op[(size_t)query * 512 + 32 + col] = __float2bfloat16(o1[r] * li);
  }
}

// ---------------- LayerNorm on bf16 sum -> bf16 h ----------------
__global__ __launch_bounds__(128)
void ln_kernel(const __hip_bfloat16* __restrict__ in, const float* __restrict__ g,
               const float* __restrict__ be, __hip_bfloat16* __restrict__ hbf) {
  const int row = blockIdx.x;
  const int tid = threadIdx.x;
  const int d = tid * 4;
  __shared__ float red[4];
  const size_t off = (size_t)row * 512 + d;
  const uint2 pu = *(const uint2*)&in[off];
  const __hip_bfloat16* ph = (const __hip_bfloat16*)&pu;
  float a[4];
#pragma unroll
  for (int j = 0; j < 4; ++j) a[j] = __bfloat162float(ph[j]);
  float s = a[0] + a[1] + a[2] + a[3];
  float q = a[0] * a[0] + a[1] * a[1] + a[2] * a[2] + a[3] * a[3];
#pragma unroll
  for (int o2 = 1; o2 < 64; o2 <<= 1) {
    s += __shfl_xor(s, o2);
    q += __shfl_xor(q, o2);
  }
  const int w = tid >> 6;
  if ((tid & 63) == 0) { red[w * 2] = s; red[w * 2 + 1] = q; }
  __syncthreads();
  s = red[0] + red[2]; q = red[1] + red[3];
  const float mean = s * (1.f / 512.f);
  const float var = q * (1.f / 512.f) - mean * mean;
  const float rstd = rsqrtf(var + 1e-5f);
  const float4 gg = *(const float4*)&g[d];
  const float4 bb = *(const float4*)&be[d];
  __hip_bfloat16 hb[4] = {
      __float2bfloat16((a[0] - mean) * rstd * gg.x + bb.x),
      __float2bfloat16((a[1] - mean) * rstd * gg.y + bb.y),
      __float2bfloat16((a[2] - mean) * rstd * gg.z + bb.z),
      __float2bfloat16((a[3] - mean) * rstd * gg.w + bb.w)};
  *(uint2*)&hbf[off] = *(uint2*)hb;
}

// ---------------- output heads (bf16 h) ----------------
__global__ __launch_bounds__(256)
void head_kernel(const __hip_bfloat16* __restrict__ hbf, const float* __restrict__ sW,
                 const float* __restrict__ sb, const float* __restrict__ lW,
                 const float* __restrict__ lb, float* __restrict__ out) {
  const int tid = threadIdx.x;
  for (int i = tid; i < 4096; i += 256) {
    const int bb = i >> 9, d = i & 511;
    out[48 + i] = __bfloat162float(hbf[(size_t)bb * 2048 * 512 + d]);
  }
  if (tid < 192) {
    const int g = tid >> 2, s4 = tid & 3;
    const int which = g / 24, rem = g % 24;
    const int bb = rem / 3, j = rem % 3;
    const float* W = which ? lW : sW;
    const float* bias = which ? lb : sb;
    const __hip_bfloat16* cls = hbf + (size_t)bb * 2048 * 512;
    float acc = 0.f;
    for (int d = s4; d < 512; d += 4) acc += __bfloat162float(cls[d]) * W[d * 3 + j];
    acc += __shfl_xor(acc, 1);
    acc += __shfl_xor(acc, 2);
    if (s4 == 0) out[which * 24 + bb * 3 + j] = acc + bias[j];
  }
}

extern "C" void kernel_launch(void* const* d_in, const int* in_sizes, int n_in,
                              void* d_out, int out_size, void* d_ws, size_t ws_size,
                              hipStream_t stream) {
  (void)in_sizes; (void)n_in; (void)out_size; (void)ws_size;
  const int* x = (const int*)d_in[0];
  const float* embed = (const float*)d_in[1];
  const float* pe = (const float*)d_in[2];
  const float* Wq = (const float*)d_in[3];
  const float* bq = (const float*)d_in[4];
  const float* Wk = (const float*)d_in[5];
  const float* bk = (const float*)d_in[6];
  const float* Wv = (const float*)d_in[7];
  const float* bvv = (const float*)d_in[8];
  const float* Wo = (const float*)d_in[9];
  const float* bo = (const float*)d_in[10];
  const float* ln1g = (const float*)d_in[11];
  const float* ln1b = (const float*)d_in[12];
  const float* W1 = (const float*)d_in[13];
  const float* b1 = (const float*)d_in[14];
  const float* W2 = (const float*)d_in[15];
  const float* b2 = (const float*)d_in[16];
  const float* ln2g = (const float*)d_in[17];
  const float* ln2b = (const float*)d_in[18];
  const float* sW = (const float*)d_in[19];
  const float* sb = (const float*)d_in[20];
  const float* lW = (const float*)d_in[21];
  const float* lb = (const float*)d_in[22];
  float* out = (float*)d_out;

  constexpr int L = 6, Dm = 512, F = 2048, B = 8, T = 2048;
  constexpr int M = B * T;
  constexpr int QS = 1536;

  char* w = (char*)d_ws;
  auto alloc = [&](size_t bytes) {
    char* p = w; w += (bytes + 255) & ~(size_t)255; return p;
  };
  __hip_bfloat16* wqkvt = (__hip_bfloat16*)alloc((size_t)L * QS * Dm * 2);  // [L][1536][512]
  __hip_bfloat16* wot = (__hip_bfloat16*)alloc((size_t)L * Dm * Dm * 2);
  __hip_bfloat16* w1t = (__hip_bfloat16*)alloc((size_t)L * Dm * F * 2);
  __hip_bfloat16* w2t = (__hip_bfloat16*)alloc((size_t)L * Dm * F * 2);
  float* bqkv = (float*)alloc((size_t)L * QS * 4);
  __hip_bfloat16* hbf = (__hip_bfloat16*)alloc((size_t)M * Dm * 2);
  // regionA (64MB): {vtg@0, attno@16MB} then ffn1@0
  char* regionA = alloc((size_t)M * F * 2);
  __hip_bfloat16* vtg = (__hip_bfloat16*)regionA;
  __hip_bfloat16* attno = (__hip_bfloat16*)(regionA + (size_t)M * Dm * 2);
  __hip_bfloat16* ffn1 = (__hip_bfloat16*)regionA;
  // regionB (48MB): qkv, later bf16 sum tmp
  char* regionB = alloc((size_t)M * QS * 2);
  __hip_bfloat16* qkvb = (__hip_bfloat16*)regionB;
  __hip_bfloat16* tmpb = (__hip_bfloat16*)regionB;
  float* kbias = (float*)alloc((size_t)M * 4);
  unsigned* tmask = (unsigned*)alloc(64);

  const size_t DD = (size_t)Dm * Dm;
  wtrans_kernel<<<dim3(8, 8, L), 256, 0, stream>>>(Wq, wqkvt, Dm, Dm, DD, (size_t)QS * Dm);
  wtrans_kernel<<<dim3(8, 8, L), 256, 0, stream>>>(Wk, wqkvt + DD, Dm, Dm, DD, (size_t)QS * Dm);
  wtrans_kernel<<<dim3(8, 8, L), 256, 0, stream>>>(Wv, wqkvt + 2 * DD, Dm, Dm, DD, (size_t)QS * Dm);
  wtrans_kernel<<<dim3(8, 8, L), 256, 0, stream>>>(Wo, wot, Dm, Dm, DD, DD);
  wtrans_kernel<<<dim3(8, 32, L), 256, 0, stream>>>(W1, w1t, Dm, F, (size_t)Dm * F, (size_t)Dm * F);
  wtrans_kernel<<<dim3(32, 8, L), 256, 0, stream>>>(W2, w2t, F, Dm, (size_t)Dm * F, (size_t)Dm * F);
  bcat_kernel<<<L, 512, 0, stream>>>(bq, bk, bvv, bqkv);
  kbias_kernel<<<M / 256, 256, 0, stream>>>(x, kbias);
  tmask_kernel<<<1, 256, 0, stream>>>(x, tmask);
  embed_kernel<<<M, 128, 0, stream>>>(x, embed, pe, hbf);

  for (int l = 0; l < L; ++l) {
    const __hip_bfloat16* wqkv_ = wqkvt + (size_t)l * QS * Dm;
    const __hip_bfloat16* wo_ = wot + (size_t)l * Dm * Dm;
    const __hip_bfloat16* w1_ = w1t + (size_t)l * Dm * F;
    const __hip_bfloat16* w2_ = w2t + (size_t)l * Dm * F;

    gemm_kernel<false, false><<<dim3(128, 12), 256, 0, stream>>>(hbf, wqkv_, bqkv + l * QS, nullptr, qkvb, M, QS, Dm);
    vtrans_kernel<<<dim3(32, 64), 256, 0, stream>>>(qkvb, vtg);
    attn10_kernel<<<512, 512, 0, stream>>>(qkvb, vtg, kbias, tmask, attno);
    gemm_kernel<false, true><<<dim3(128, 4), 256, 0, stream>>>(attno, wo_, bo + l * Dm, hbf, tmpb, M, Dm, Dm);
    ln_kernel<<<M, 128, 0, stream>>>(tmpb, ln1g + l * Dm, ln1b + l * Dm, hbf);
    gemm_kernel<true, false><<<dim3(128, 16), 256, 0, stream>>>(hbf, w1_, b1 + l * F, nullptr, ffn1, M, F, Dm);
    gemm_kernel<false, true><<<dim3(128, 4), 256, 0, stream>>>(ffn1, w2_, b2 + l * Dm, hbf, tmpb, M, Dm, F);
    ln_kernel<<<M, 128, 0, stream>>>(tmpb, ln2g + l * Dm, ln2b + l * Dm, hbf);
  }
  head_kernel<<<1, 256, 0, stream>>>(hbf, sW, sb, lW, lb, out);
}

// Round 13
// 1492.712 us; speedup vs baseline: 1.0206x; 1.0206x over previous
//
#include <hip/hip_runtime.h>
#include <hip/hip_bf16.h>

typedef __bf16 bf16x8 __attribute__((ext_vector_type(8)));
typedef float f32x4 __attribute__((ext_vector_type(4)));
typedef float f32x16 __attribute__((ext_vector_type(16)));
typedef short s16x8 __attribute__((ext_vector_type(8)));
typedef unsigned u32x4 __attribute__((ext_vector_type(4)));

#define LOG2E 1.44269504088896f

__device__ __forceinline__ void gll16(const void* g, void* l) {
  __builtin_amdgcn_global_load_lds((const __attribute__((address_space(1))) void*)g,
                                   (__attribute__((address_space(3))) void*)l, 16, 0, 0);
}

__device__ __forceinline__ unsigned cvt_pk_bf16(float lo, float hi_) {
  unsigned r;
  asm("v_cvt_pk_bf16_f32 %0, %1, %2" : "=v"(r) : "v"(lo), "v"(hi_));
  return r;
}
__device__ __forceinline__ void pswap(unsigned& a, unsigned& b) {
  asm("v_permlane32_swap_b32 %0, %1" : "+v"(a), "+v"(b));
}

// swizzle for the V-transpose kernel's internal LDS tile
__device__ __forceinline__ int swzv(int row, int cbyte) {
  return (row * 128 + cbyte) ^ (((row >> 3) & 7) << 4);
}

// ---------------- weight transpose f32[K][N] -> bf16[N][K] ----------------
__global__ __launch_bounds__(256)
void wtrans_kernel(const float* __restrict__ in, __hip_bfloat16* __restrict__ out,
                   int K, int N, size_t lstride_in, size_t lstride_out) {
  __shared__ float tile[64][65];
  const size_t mi = (size_t)blockIdx.z * lstride_in;
  const size_t mo = (size_t)blockIdx.z * lstride_out;
  const int k0 = blockIdx.x * 64, n0 = blockIdx.y * 64;
  const int t = threadIdx.x;
  const int r = t >> 4, c = (t & 15) * 4;
#pragma unroll
  for (int it = 0; it < 4; ++it) {
    const float4 v = *(const float4*)&in[mi + (size_t)(k0 + it * 16 + r) * N + n0 + c];
    tile[it * 16 + r][c + 0] = v.x; tile[it * 16 + r][c + 1] = v.y;
    tile[it * 16 + r][c + 2] = v.z; tile[it * 16 + r][c + 3] = v.w;
  }
  __syncthreads();
#pragma unroll
  for (int it = 0; it < 4; ++it) {
    const int n = it * 16 + r;
    __hip_bfloat16 hb[4];
#pragma unroll
    for (int j = 0; j < 4; ++j) hb[j] = __float2bfloat16(tile[c + j][n]);
    *(uint2*)&out[mo + (size_t)(n0 + n) * K + k0 + c] = *(uint2*)hb;
  }
}

// ---------------- key bias + per-tile mask bitmasks ----------------
__global__ void kbias_kernel(const int* __restrict__ x, float* __restrict__ kb) {
  const int i = blockIdx.x * 256 + threadIdx.x;
  kb[i] = (x[i] == 0) ? -1e30f : 0.f;
}

// tm[b*2+0] = bit kt set if 64-key tile kt fully padded; tm[b*2+1] = partial pad
__global__ void tmask_kernel(const int* __restrict__ x, unsigned* __restrict__ tm) {
  const int tid = threadIdx.x;
  const int w = tid >> 6, lane = tid & 63;
  const int b = w * 2 + (lane >> 5), kt = lane & 31;
  int all64 = 1, any = 0;
  for (int i = 0; i < 64; ++i) {
    const int v = (x[b * 2048 + kt * 64 + i] == 0);
    any |= v; all64 &= v;
  }
  const unsigned long long bf = __ballot(all64);
  const unsigned long long bp = __ballot(any && !all64);
  if (lane == 0) { tm[(w * 2) * 2] = (unsigned)bf; tm[(w * 2) * 2 + 1] = (unsigned)bp; }
  if (lane == 32) { tm[(w * 2 + 1) * 2] = (unsigned)(bf >> 32); tm[(w * 2 + 1) * 2 + 1] = (unsigned)(bp >> 32); }
}

// ---------------- bias concat [L][512]x3 -> [L][1536] ----------------
__global__ void bcat_kernel(const float* __restrict__ bq, const float* __restrict__ bk,
                            const float* __restrict__ bv, float* __restrict__ o) {
  const int l = blockIdx.x, t = threadIdx.x;
  o[l * 1536 + t] = bq[l * 512 + t];
  o[l * 1536 + 512 + t] = bk[l * 512 + t];
  o[l * 1536 + 1024 + t] = bv[l * 512 + t];
}

// ---------------- embedding + positional (bf16 h only) ----------------
__global__ __launch_bounds__(128)
void embed_kernel(const int* __restrict__ x, const float* __restrict__ emb,
                  const float* __restrict__ pe, __hip_bfloat16* __restrict__ hbf) {
  const int row = blockIdx.x;
  const int t = row & 2047;
  const int tok = x[row];
  const int d = threadIdx.x * 4;
  const float4 e = *(const float4*)&emb[(size_t)tok * 512 + d];
  const float4 p = *(const float4*)&pe[(size_t)t * 512 + d];
  __hip_bfloat16 hb[4] = {__float2bfloat16(e.x + p.x), __float2bfloat16(e.y + p.y),
                          __float2bfloat16(e.z + p.z), __float2bfloat16(e.w + p.w)};
  *(uint2*)&hbf[(size_t)row * 512 + d] = *(uint2*)hb;
}

// ---------------- 128^2 GEMM: C = act(A @ Bt^T + bias [+ res]) -> bf16 ----------------
// plain blockIdx mapping: default x-fastest dispatch already keeps the B-panel
// L2-resident per XCD and A is L3-resident (16MB << 256MB) — XCD remap hurt (R12).
template <bool RELU, bool ADDRES>
__global__ __launch_bounds__(256, 4)
void gemm_kernel(const __hip_bfloat16* __restrict__ A, const __hip_bfloat16* __restrict__ Bt,
                 const float* __restrict__ bias, const __hip_bfloat16* __restrict__ res,
                 __hip_bfloat16* __restrict__ Cb, int M, int N, int K) {
  constexpr int BK = 32;
  __shared__ __hip_bfloat16 Ash[2][128 * BK];
  __shared__ __hip_bfloat16 Bsh[2][128 * BK];
  const int m0 = blockIdx.x * 128, n0 = blockIdx.y * 128;
  const int tid = threadIdx.x;
  const int lane = tid & 63, wid = tid >> 6;
  const int wr = wid >> 1, wc = wid & 1;
  const int cl = lane & 15, gr = lane >> 4;

  const int ar = tid >> 2;
  const int ac = (tid & 3) << 3;
  const __hip_bfloat16* Ag = A + (size_t)(m0 + ar) * K + ac;
  const __hip_bfloat16* Bg = Bt + (size_t)(n0 + ar) * K + ac;
  const int ldst = tid * 8;

  f32x4 acc[4][4] = {};
  const int KT = K / BK;

  auto stage = [&](int buf, int kt) {
    const size_t ko = (size_t)kt * BK;
    gll16(Ag + ko, &Ash[buf][ldst]);
    gll16(Ag + ko + (size_t)64 * K, &Ash[buf][2048 + ldst]);
    gll16(Bg + ko, &Bsh[buf][ldst]);
    gll16(Bg + ko + (size_t)64 * K, &Bsh[buf][2048 + ldst]);
  };

  stage(0, 0);
  __syncthreads();
  int cur = 0;
  for (int kt = 0; kt < KT; ++kt) {
    if (kt + 1 < KT) stage(cur ^ 1, kt + 1);
    bf16x8 aF[4], bF[4];
#pragma unroll
    for (int i = 0; i < 4; ++i) {
      aF[i] = *(const bf16x8*)&Ash[cur][(wr * 64 + i * 16 + cl) * BK + gr * 8];
      bF[i] = *(const bf16x8*)&Bsh[cur][(wc * 64 + i * 16 + cl) * BK + gr * 8];
    }
#pragma unroll
    for (int i = 0; i < 4; ++i)
#pragma unroll
      for (int j = 0; j < 4; ++j)
        acc[i][j] = __builtin_amdgcn_mfma_f32_16x16x32_bf16(aF[i], bF[j], acc[i][j], 0, 0, 0);
    __syncthreads();
    cur ^= 1;
  }

  float bv[4];
#pragma unroll
  for (int j = 0; j < 4; ++j) bv[j] = bias[n0 + wc * 64 + j * 16 + cl];
#pragma unroll
  for (int i = 0; i < 4; ++i) {
    const int rowb = m0 + wr * 64 + i * 16 + gr * 4;
#pragma unroll
    for (int rr = 0; rr < 4; ++rr) {
      const size_t ro = (size_t)(rowb + rr) * N;
#pragma unroll
      for (int j = 0; j < 4; ++j) {
        float v = acc[i][j][rr] + bv[j];
        const int col = n0 + wc * 64 + j * 16 + cl;
        if (ADDRES) v += __bfloat162float(res[ro + col]);
        if (RELU) v = v > 0.f ? v : 0.f;
        Cb[ro + col] = __float2bfloat16(v);
      }
    }
  }
}

// ---------------- V transpose: qkv[M][1536] (V section) -> vt[b*8+h][64][2048] ----------------
__global__ __launch_bounds__(256)
void vtrans_kernel(const __hip_bfloat16* __restrict__ qkv, __hip_bfloat16* __restrict__ vt) {
  constexpr int T = 2048, QS = 1536;
  __shared__ __hip_bfloat16 tile[64 * 64];
  const int tt = blockIdx.x, bh = blockIdx.y;
  const int b = bh >> 3, h = bh & 7;
  const int tid = threadIdx.x;
  const int r = tid >> 2, c0 = (tid & 3) * 16;
  const __hip_bfloat16* src = qkv + ((size_t)(b * T + tt * 64 + r)) * QS + 1024 + h * 64 + c0;
  *(bf16x8*)((char*)tile + swzv(r, c0 * 2)) = *(const bf16x8*)src;
  *(bf16x8*)((char*)tile + swzv(r, c0 * 2 + 16)) = *(const bf16x8*)(src + 8);
  __syncthreads();
  __hip_bfloat16 buf[16];
#pragma unroll
  for (int j = 0; j < 16; ++j)
    buf[j] = *(__hip_bfloat16*)((char*)tile + swzv(c0 + j, r * 2));
  __hip_bfloat16* dst = vt + ((size_t)(bh * 64 + r)) * T + tt * 64 + c0;
  *(uint4*)dst = ((uint4*)buf)[0];
  *(uint4*)(dst + 8) = ((uint4*)buf)[1];
}

// ---------------- flash attention: 8 waves, Q-block=256, KV tile=128, no-max softmax ----
__global__ __launch_bounds__(512, 2)
void attn10_kernel(const __hip_bfloat16* __restrict__ qkv, const __hip_bfloat16* __restrict__ Vt,
                   const float* __restrict__ kbias, const unsigned* __restrict__ tmaskg,
                   __hip_bfloat16* __restrict__ Og) {
  constexpr int T = 2048, NT = T / 128, QS = 1536;
  __shared__ __hip_bfloat16 Ks[2][128 * 64];   // 32KB: 128 key-rows x 64 d
  __shared__ __hip_bfloat16 Vs[2][64 * 128];   // 32KB: 64 d-rows x 128 keys
  __shared__ float bc[8][32];
  const int bid = blockIdx.x;
  const int wg = (bid & 7) * 64 + (bid >> 3);
  const int qb = wg & 7, bh = wg >> 3;
  const int b = bh >> 3, h = bh & 7;
  const int tid = threadIdx.x;
  const int w = tid >> 6, lane = tid & 63;
  const int col = lane & 31, hi = lane >> 5;
  const unsigned fullm = tmaskg[b * 2], partm = tmaskg[b * 2 + 1];

  // K staging (rule #21: linear LDS dest, inverse-swizzled global source)
  const int sr = tid >> 3;                    // key row 0..63 (and +64)
  const int sc = 8 * ((tid & 7) ^ (sr & 7));
  const __hip_bfloat16* kp = qkv + ((size_t)(b * T + sr)) * QS + 512 + h * 64 + sc;
  // V staging: d-row vr (and +32), 16 chunks per 256B row, 4-bit swizzle
  const int vr = tid >> 4;                    // 0..31
  const int vsc = 8 * ((tid & 15) ^ (vr & 15));
  const __hip_bfloat16* vp = Vt + ((size_t)(bh * 64 + vr)) * T + vsc;

  auto stage = [&](int buf, int kt) {
    const size_t ko = (size_t)kt * 128 * QS;
    gll16(kp + ko, (char*)Ks[buf] + tid * 16);
    gll16(kp + ko + (size_t)64 * QS, (char*)Ks[buf] + 8192 + tid * 16);
    const int vo = kt * 128;
    gll16(vp + vo, (char*)Vs[buf] + tid * 16);
    gll16(vp + vo + (size_t)32 * T, (char*)Vs[buf] + 8192 + tid * 16);
  };

  // Q fragments (B-operand), pre-scaled by 0.125*log2(e)
  const float qscale = 0.125f * LOG2E;
  s16x8 qf[4];
  {
    const __hip_bfloat16* qptr =
        qkv + ((size_t)(b * T + qb * 256 + w * 32 + col)) * QS + h * 64 + 8 * hi;
#pragma unroll
    for (int ks = 0; ks < 4; ++ks) {
      s16x8 raw = *(const s16x8*)(qptr + ks * 16);
#pragma unroll
      for (int j = 0; j < 8; ++j) {
        const unsigned u = ((unsigned)(unsigned short)raw[j]) << 16;
        const float f = __uint_as_float(u) * qscale;
        const __hip_bfloat16 hb = __float2bfloat16(f);
        raw[j] = *(const short*)&hb;
      }
      qf[ks] = raw;
    }
  }

  stage(0, 0);
  __syncthreads();

  f32x16 o0 = {}, o1 = {};
  f32x4 lacc = {};

  for (int kt = 0; kt < NT; ++kt) {
    const int cur = kt & 1;
    if (kt + 1 < NT) stage(cur ^ 1, kt + 1);

    const char* kbase = (const char*)Ks[cur];
    const char* vbase = (const char*)Vs[cur];
    const float* kbp = kbias + (size_t)b * T + kt * 128;

#pragma unroll
    for (int kb2 = 0; kb2 < 4; ++kb2) {
      const int mb = kt * 2 + (kb2 >> 1);     // 64-key mask bit
      if ((fullm >> mb) & 1) continue;

      // S^T = K_chunk(32 keys) . Q^T (lane's col = its query), log2 domain
      f32x16 s = {};
      {
        const char* khalf = kbase + kb2 * 4096;
        __builtin_amdgcn_s_setprio(1);
#pragma unroll
        for (int ks = 0; ks < 4; ++ks) {
          const int sl = ((2 * ks + hi) ^ (col & 7)) * 16;
          const bf16x8 k8 = *(const bf16x8*)(khalf + col * 128 + sl);
          s = __builtin_amdgcn_mfma_f32_32x32x16_bf16(k8, *(const bf16x8*)&qf[ks], s, 0, 0, 0);
        }
        __builtin_amdgcn_s_setprio(0);
      }

      if ((partm >> mb) & 1) {
#pragma unroll
        for (int r = 0; r < 16; ++r) {
          const int k16 = (r & 3) + 8 * (r >> 2) + 4 * hi;
          s[r] += kbp[kb2 * 32 + k16];
        }
      }

      // raw v_exp_f32 (scores bounded; -1e30 -> 0); defer l-reduction to epilogue
#pragma unroll
      for (int r = 0; r < 16; ++r) {
        s[r] = __builtin_amdgcn_exp2f(s[r]);
        lacc[r & 3] += s[r];
      }

      // P -> bf16 A-frags (cvt_pk + permlane32_swap), PV accumulate
#pragma unroll
      for (int half = 0; half < 2; ++half) {
        const int ks = kb2 * 2 + half;        // key-chunk pair index 0..7
        const int rb = half * 8;
        unsigned wa = cvt_pk_bf16(s[rb + 0], s[rb + 1]);
        unsigned wb = cvt_pk_bf16(s[rb + 2], s[rb + 3]);
        unsigned wc = cvt_pk_bf16(s[rb + 4], s[rb + 5]);
        unsigned wd = cvt_pk_bf16(s[rb + 6], s[rb + 7]);
        pswap(wa, wc);
        pswap(wb, wd);
        const u32x4 paw = {wa, wb, wc, wd};
        const bf16x8 pa = __builtin_bit_cast(bf16x8, paw);
        const int sl = ((2 * ks + hi) ^ (col & 15)) * 16;
        const bf16x8 v0 = *(const bf16x8*)(vbase + col * 256 + sl);
        const bf16x8 v1 = *(const bf16x8*)(vbase + 8192 + col * 256 + sl);
        __builtin_amdgcn_s_setprio(1);
        o0 = __builtin_amdgcn_mfma_f32_32x32x16_bf16(pa, v0, o0, 0, 0, 0);
        o1 = __builtin_amdgcn_mfma_f32_32x32x16_bf16(pa, v1, o1, 0, 0, 0);
        __builtin_amdgcn_s_setprio(0);
      }
    }
    __syncthreads();
  }

  // epilogue: l-reduction (tree over 4 + half-swap), 1/l broadcast, store
  float sm[4];
#pragma unroll
  for (int r = 0; r < 4; ++r) sm[r] = lacc[r];
  sm[0] += sm[2]; sm[1] += sm[3]; sm[0] += sm[1];
  const float lrun = sm[0] + __shfl_xor(sm[0], 32);

  bc[w][col] = 1.f / lrun;
  __hip_bfloat16* op = Og + ((size_t)(b * T + qb * 256 + w * 32)) * 512 + h * 64;
#pragma unroll
  for (int r = 0; r < 16; ++r) {
    const int query = (r & 3) + 8 * (r >> 2) + 4 * hi;
    const float li = bc[w][query];
    op[(size_t)query * 512 + col] = __float2bfloat16(o0[r] * li);
    op[(size_t)query * 512 + 32 + col] = __float2bfloat16(o1[r] * li);
  }
}

// ---------------- LayerNorm on bf16 sum -> bf16 h ----------------
__global__ __launch_bounds__(128)
void ln_kernel(const __hip_bfloat16* __restrict__ in, const float* __restrict__ g,
               const float* __restrict__ be, __hip_bfloat16* __restrict__ hbf) {
  const int row = blockIdx.x;
  const int tid = threadIdx.x;
  const int d = tid * 4;
  __shared__ float red[4];
  const size_t off = (size_t)row * 512 + d;
  const uint2 pu = *(const uint2*)&in[off];
  const __hip_bfloat16* ph = (const __hip_bfloat16*)&pu;
  float a[4];
#pragma unroll
  for (int j = 0; j < 4; ++j) a[j] = __bfloat162float(ph[j]);
  float s = a[0] + a[1] + a[2] + a[3];
  float q = a[0] * a[0] + a[1] * a[1] + a[2] * a[2] + a[3] * a[3];
#pragma unroll
  for (int o2 = 1; o2 < 64; o2 <<= 1) {
    s += __shfl_xor(s, o2);
    q += __shfl_xor(q, o2);
  }
  const int w = tid >> 6;
  if ((tid & 63) == 0) { red[w * 2] = s; red[w * 2 + 1] = q; }
  __syncthreads();
  s = red[0] + red[2]; q = red[1] + red[3];
  const float mean = s * (1.f / 512.f);
  const float var = q * (1.f / 512.f) - mean * mean;
  const float rstd = rsqrtf(var + 1e-5f);
  const float4 gg = *(const float4*)&g[d];
  const float4 bb = *(const float4*)&be[d];
  __hip_bfloat16 hb[4] = {
      __float2bfloat16((a[0] - mean) * rstd * gg.x + bb.x),
      __float2bfloat16((a[1] - mean) * rstd * gg.y + bb.y),
      __float2bfloat16((a[2] - mean) * rstd * gg.z + bb.z),
      __float2bfloat16((a[3] - mean) * rstd * gg.w + bb.w)};
  *(uint2*)&hbf[off] = *(uint2*)hb;
}

// ---------------- output heads (bf16 h) ----------------
__global__ __launch_bounds__(256)
void head_kernel(const __hip_bfloat16* __restrict__ hbf, const float* __restrict__ sW,
                 const float* __restrict__ sb, const float* __restrict__ lW,
                 const float* __restrict__ lb, float* __restrict__ out) {
  const int tid = threadIdx.x;
  for (int i = tid; i < 4096; i += 256) {
    const int bb = i >> 9, d = i & 511;
    out[48 + i] = __bfloat162float(hbf[(size_t)bb * 2048 * 512 + d]);
  }
  if (tid < 192) {
    const int g = tid >> 2, s4 = tid & 3;
    const int which = g / 24, rem = g % 24;
    const int bb = rem / 3, j = rem % 3;
    const float* W = which ? lW : sW;
    const float* bias = which ? lb : sb;
    const __hip_bfloat16* cls = hbf + (size_t)bb * 2048 * 512;
    float acc = 0.f;
    for (int d = s4; d < 512; d += 4) acc += __bfloat162float(cls[d]) * W[d * 3 + j];
    acc += __shfl_xor(acc, 1);
    acc += __shfl_xor(acc, 2);
    if (s4 == 0) out[which * 24 + bb * 3 + j] = acc + bias[j];
  }
}

extern "C" void kernel_launch(void* const* d_in, const int* in_sizes, int n_in,
                              void* d_out, int out_size, void* d_ws, size_t ws_size,
                              hipStream_t stream) {
  (void)in_sizes; (void)n_in; (void)out_size; (void)ws_size;
  const int* x = (const int*)d_in[0];
  const float* embed = (const float*)d_in[1];
  const float* pe = (const float*)d_in[2];
  const float* Wq = (const float*)d_in[3];
  const float* bq = (const float*)d_in[4];
  const float* Wk = (const float*)d_in[5];
  const float* bk = (const float*)d_in[6];
  const float* Wv = (const float*)d_in[7];
  const float* bvv = (const float*)d_in[8];
  const float* Wo = (const float*)d_in[9];
  const float* bo = (const float*)d_in[10];
  const float* ln1g = (const float*)d_in[11];
  const float* ln1b = (const float*)d_in[12];
  const float* W1 = (const float*)d_in[13];
  const float* b1 = (const float*)d_in[14];
  const float* W2 = (const float*)d_in[15];
  const float* b2 = (const float*)d_in[16];
  const float* ln2g = (const float*)d_in[17];
  const float* ln2b = (const float*)d_in[18];
  const float* sW = (const float*)d_in[19];
  const float* sb = (const float*)d_in[20];
  const float* lW = (const float*)d_in[21];
  const float* lb = (const float*)d_in[22];
  float* out = (float*)d_out;

  constexpr int L = 6, Dm = 512, F = 2048, B = 8, T = 2048;
  constexpr int M = B * T;
  constexpr int QS = 1536;

  char* w = (char*)d_ws;
  auto alloc = [&](size_t bytes) {
    char* p = w; w += (bytes + 255) & ~(size_t)255; return p;
  };
  __hip_bfloat16* wqkvt = (__hip_bfloat16*)alloc((size_t)L * QS * Dm * 2);  // [L][1536][512]
  __hip_bfloat16* wot = (__hip_bfloat16*)alloc((size_t)L * Dm * Dm * 2);
  __hip_bfloat16* w1t = (__hip_bfloat16*)alloc((size_t)L * Dm * F * 2);
  __hip_bfloat16* w2t = (__hip_bfloat16*)alloc((size_t)L * Dm * F * 2);
  float* bqkv = (float*)alloc((size_t)L * QS * 4);
  __hip_bfloat16* hbf = (__hip_bfloat16*)alloc((size_t)M * Dm * 2);
  // regionA (64MB): {vtg@0, attno@16MB} then ffn1@0
  char* regionA = alloc((size_t)M * F * 2);
  __hip_bfloat16* vtg = (__hip_bfloat16*)regionA;
  __hip_bfloat16* attno = (__hip_bfloat16*)(regionA + (size_t)M * Dm * 2);
  __hip_bfloat16* ffn1 = (__hip_bfloat16*)regionA;
  // regionB (48MB): qkv, later bf16 sum tmp
  char* regionB = alloc((size_t)M * QS * 2);
  __hip_bfloat16* qkvb = (__hip_bfloat16*)regionB;
  __hip_bfloat16* tmpb = (__hip_bfloat16*)regionB;
  float* kbias = (float*)alloc((size_t)M * 4);
  unsigned* tmask = (unsigned*)alloc(64);

  const size_t DD = (size_t)Dm * Dm;
  wtrans_kernel<<<dim3(8, 8, L), 256, 0, stream>>>(Wq, wqkvt, Dm, Dm, DD, (size_t)QS * Dm);
  wtrans_kernel<<<dim3(8, 8, L), 256, 0, stream>>>(Wk, wqkvt + DD, Dm, Dm, DD, (size_t)QS * Dm);
  wtrans_kernel<<<dim3(8, 8, L), 256, 0, stream>>>(Wv, wqkvt + 2 * DD, Dm, Dm, DD, (size_t)QS * Dm);
  wtrans_kernel<<<dim3(8, 8, L), 256, 0, stream>>>(Wo, wot, Dm, Dm, DD, DD);
  wtrans_kernel<<<dim3(8, 32, L), 256, 0, stream>>>(W1, w1t, Dm, F, (size_t)Dm * F, (size_t)Dm * F);
  wtrans_kernel<<<dim3(32, 8, L), 256, 0, stream>>>(W2, w2t, F, Dm, (size_t)Dm * F, (size_t)Dm * F);
  bcat_kernel<<<L, 512, 0, stream>>>(bq, bk, bvv, bqkv);
  kbias_kernel<<<M / 256, 256, 0, stream>>>(x, kbias);
  tmask_kernel<<<1, 256, 0, stream>>>(x, tmask);
  embed_kernel<<<M, 128, 0, stream>>>(x, embed, pe, hbf);

  for (int l = 0; l < L; ++l) {
    const __hip_bfloat16* wqkv_ = wqkvt + (size_t)l * QS * Dm;
    const __hip_bfloat16* wo_ = wot + (size_t)l * Dm * Dm;
    const __hip_bfloat16* w1_ = w1t + (size_t)l * Dm * F;
    const __hip_bfloat16* w2_ = w2t + (size_t)l * Dm * F;

    gemm_kernel<false, false><<<dim3(128, 12), 256, 0, stream>>>(hbf, wqkv_, bqkv + l * QS, nullptr, qkvb, M, QS, Dm);
    vtrans_kernel<<<dim3(32, 64), 256, 0, stream>>>(qkvb, vtg);
    attn10_kernel<<<512, 512, 0, stream>>>(qkvb, vtg, kbias, tmask, attno);
    gemm_kernel<false, true><<<dim3(128, 4), 256, 0, stream>>>(attno, wo_, bo + l * Dm, hbf, tmpb, M, Dm, Dm);
    ln_kernel<<<M, 128, 0, stream>>>(tmpb, ln1g + l * Dm, ln1b + l * Dm, hbf);
    gemm_kernel<true, false><<<dim3(128, 16), 256, 0, stream>>>(hbf, w1_, b1 + l * F, nullptr, ffn1, M, F, Dm);
    gemm_kernel<false, true><<<dim3(128, 4), 256, 0, stream>>>(ffn1, w2_, b2 + l * Dm, hbf, tmpb, M, Dm, F);
    ln_kernel<<<M, 128, 0, stream>>>(tmpb, ln2g + l * Dm, ln2b + l * Dm, hbf);
  }
  head_kernel<<<1, 256, 0, stream>>>(hbf, sW, sb, lW, lb, out);
}